// Round 9
// baseline (541.819 us; speedup 1.0000x reference)
//
#include <hip/hip_runtime.h>

typedef __attribute__((ext_vector_type(4))) float f32x4;
typedef __attribute__((ext_vector_type(8))) short s16x8;

#define IN_F 512
#define OUT_F 512
#define STYLE_F 256

__device__ __forceinline__ unsigned short f2bf(float f) {
    unsigned int u = __builtin_bit_cast(unsigned int, f);
    u += 0x7FFFu + ((u >> 16) & 1u);   // round-to-nearest-even
    return (unsigned short)(u >> 16);
}

// pack 8 fp32 -> 8 bf16 (RNE) via v_cvt_pk_bf16_f32
__device__ __forceinline__ s16x8 cvt8(f32x4 a, f32x4 b) {
    union { unsigned int w[4]; s16x8 v; } u;
    asm("v_cvt_pk_bf16_f32 %0, %1, %2" : "=v"(u.w[0]) : "v"(a[0]), "v"(a[1]));
    asm("v_cvt_pk_bf16_f32 %0, %1, %2" : "=v"(u.w[1]) : "v"(a[2]), "v"(a[3]));
    asm("v_cvt_pk_bf16_f32 %0, %1, %2" : "=v"(u.w[2]) : "v"(b[0]), "v"(b[1]));
    asm("v_cvt_pk_bf16_f32 %0, %1, %2" : "=v"(u.w[3]) : "v"(b[2]), "v"(b[3]));
    return u.v;
}

// ---------------- prep1: alpha/beta GEMVs (2048 dots of length 256) --------
__global__ __launch_bounds__(256) void prep1_kernel(
    const float* __restrict__ z,
    const float* __restrict__ w_alpha,
    const float* __restrict__ b_alpha,
    const float* __restrict__ w_beta,
    const float* __restrict__ b_beta,
    float* __restrict__ alpha,
    float* __restrict__ beta)
{
    int gid = blockIdx.x * 256 + threadIdx.x;
    if (gid >= 2048) return;
    int t = gid & 1023;
    int b = t >> 9;
    int i = t & 511;
    const float* zr = z + b * STYLE_F;
    const float* wr = (gid < 1024 ? w_alpha : w_beta) + i * STYLE_F;
    float acc = 0.f;
    #pragma unroll 4
    for (int kk = 0; kk < STYLE_F; kk += 4) {
        float4 zv = *reinterpret_cast<const float4*>(zr + kk);
        float4 vv = *reinterpret_cast<const float4*>(wr + kk);
        acc += zv.x * vv.x + zv.y * vv.y + zv.z * vv.z + zv.w * vv.w;
    }
    if (gid < 1024) alpha[t] = acc + b_alpha[i];
    else            beta[t]  = acc + b_beta[i];
}

// ---------------- prep2: W * alpha_b -> bf16 fragment order, per batch -----
// wfragB[b] element index = (((ks*32 + nf)*64 + lane)*8 + e)
//   holds weight[n = nf*16 + (lane&15)][k = ks*32 + (lane>>4)*8 + e] * alpha[b][k]
__global__ __launch_bounds__(256) void prep2_kernel(
    const float* __restrict__ weight,
    const float* __restrict__ alpha,
    unsigned short* __restrict__ wfragB)
{
    int gid = blockIdx.x * 256 + threadIdx.x;   // 131072 threads total
    int b = gid >> 16;                          // 65536 threads per batch
    int f = (gid & 65535) << 2;
    int e0 = f & 7;                 // 0 or 4
    int l  = (f >> 3) & 63;
    int nf = (f >> 9) & 31;
    int ks = f >> 14;               // 0..15
    int n  = nf * 16 + (l & 15);
    int k  = ks * 32 + ((l >> 4) << 3) + e0;
    float4 wv = *reinterpret_cast<const float4*>(weight + n * IN_F + k);
    float4 av = *reinterpret_cast<const float4*>(alpha + b * IN_F + k);
    ushort4 o;
    o.x = f2bf(wv.x * av.x); o.y = f2bf(wv.y * av.y);
    o.z = f2bf(wv.z * av.z); o.w = f2bf(wv.w * av.w);
    *reinterpret_cast<ushort4*>(wfragB + b * 262144 + f) = o;
}

// ---------------- main GEMM: out = x_bf16 @ (W*alpha_b)^T + beta -----------
// NO LDS, NO BARRIERS. 4096 blocks x 512 thr = 8 waves (2M x 4N), wave tile
// 32x128 = 2x8 fragments. All loads are asm-volatile global_load_dwordx4
// (compiler cannot collapse the pipeline); per-wave in-order vmcnt ledger:
//   prologue: A(0) A(1) B(0)
//   iter s:   issue B(s+1)[8], A(s+2)[4]; s_waitcnt vmcnt(W); compute s
//   W: s=0 ->12, s=1..13 ->16, s=14 ->12, s=15 ->0
// A flight = 2 iters (HBM), B flight = 1 iter (L2-resident wfragB).
__global__ __launch_bounds__(512, 2) void modlin_kernel(
    const float* __restrict__ x,
    const unsigned short* __restrict__ wfragB,
    const float* __restrict__ beta,
    float* __restrict__ out)
{
    const int tid = threadIdx.x;
    const int blk = blockIdx.x;              // 4096 blocks of 64 rows
    const int b   = blk >> 11;               // 2048 blocks per batch

    const int l  = tid & 63;
    const int w  = tid >> 6;                 // wave 0..7
    const int wm = w >> 2;                   // 0..1 (M)
    const int wn = w & 3;                    // 0..3 (N)
    const int fr = l & 15;
    const int fq = l >> 4;                   // 0..3

    // beta preload FIRST (oldest in vmcnt queue; retired by iter-0 wait)
    float bv[8];
    #pragma unroll
    for (int nf = 0; nf < 8; ++nf)
        bv[nf] = beta[b * OUT_F + wn * 128 + nf * 16 + fr];

    // A addressing: lane reads 32B (2x16B) of row (blk*64+wm*32+fr) at
    // k-bytes fq*32 + s*128. Paired instrs make dense 128B lines per row.
    const unsigned rowA = (unsigned)(blk * 64 + wm * 32 + fr);
    const unsigned vA0  = rowA * 2048u + (unsigned)fq * 32u;
    const unsigned vA1  = vA0 + 32768u;      // +16 rows
    // B addressing (L2-resident)
    const char* bbp = (const char*)wfragB + (size_t)b * 524288;
    const unsigned vob = (unsigned)(wn * 8192 + l * 16);

    f32x4 ap[3][4];      // A slots (depth: s, s+1, s+2)
    s16x8 bq[2][8];      // B slots (depth: s, s+1)
    f32x4 acc[2][8];
    #pragma unroll
    for (int i = 0; i < 2; ++i)
        #pragma unroll
        for (int j = 0; j < 8; ++j)
            acc[i][j] = (f32x4){0.f, 0.f, 0.f, 0.f};

    #define LOADA(SL, S)                                                       \
        do {                                                                   \
            asm volatile("global_load_dwordx4 %0, %1, %2 offset:%3"            \
                : "=v"(ap[SL][0]) : "v"(vA0), "s"(x), "n"((S)*128)      : "memory"); \
            asm volatile("global_load_dwordx4 %0, %1, %2 offset:%3"            \
                : "=v"(ap[SL][1]) : "v"(vA0), "s"(x), "n"((S)*128+16)   : "memory"); \
            asm volatile("global_load_dwordx4 %0, %1, %2 offset:%3"            \
                : "=v"(ap[SL][2]) : "v"(vA1), "s"(x), "n"((S)*128)      : "memory"); \
            asm volatile("global_load_dwordx4 %0, %1, %2 offset:%3"            \
                : "=v"(ap[SL][3]) : "v"(vA1), "s"(x), "n"((S)*128+16)   : "memory"); \
        } while (0)

    #define LOADB(SL, S)                                                       \
        do {                                                                   \
            unsigned voA_ = vob + (unsigned)(S) * 32768u;                      \
            unsigned voB_ = voA_ + 4096u;                                      \
            _Pragma("unroll")                                                  \
            for (int nf_ = 0; nf_ < 4; ++nf_) {                                \
                asm volatile("global_load_dwordx4 %0, %1, %2 offset:%3"        \
                    : "=v"(bq[SL][nf_])     : "v"(voA_), "s"(bbp),             \
                      "n"(nf_ * 1024) : "memory");                             \
                asm volatile("global_load_dwordx4 %0, %1, %2 offset:%3"        \
                    : "=v"(bq[SL][nf_ + 4]) : "v"(voB_), "s"(bbp),             \
                      "n"(nf_ * 1024) : "memory");                             \
            }                                                                  \
        } while (0)

    #define ITER(S, W)                                                         \
        do {                                                                   \
            if ((S) < 15) LOADB(((S) + 1) & 1, (S) + 1);                       \
            if ((S) < 14) LOADA(((S) + 2) % 3, (S) + 2);                       \
            asm volatile("s_waitcnt vmcnt(%0)" :: "n"(W) : "memory");          \
            __builtin_amdgcn_sched_barrier(0);                                 \
            s16x8 a0_ = cvt8(ap[(S) % 3][0], ap[(S) % 3][1]);                  \
            s16x8 a1_ = cvt8(ap[(S) % 3][2], ap[(S) % 3][3]);                  \
            _Pragma("unroll")                                                  \
            for (int nf_ = 0; nf_ < 8; ++nf_) {                                \
                acc[0][nf_] = __builtin_amdgcn_mfma_f32_16x16x32_bf16(         \
                    a0_, bq[(S) & 1][nf_], acc[0][nf_], 0, 0, 0);              \
                acc[1][nf_] = __builtin_amdgcn_mfma_f32_16x16x32_bf16(         \
                    a1_, bq[(S) & 1][nf_], acc[1][nf_], 0, 0, 0);              \
            }                                                                  \
        } while (0)

    // ---- prologue: A(0), A(1), B(0) in flight
    LOADA(0, 0);
    LOADA(1, 1);
    LOADB(0, 0);

    // ---- 16 k-slices, wave-private pipeline, zero barriers
    ITER(0, 12);  ITER(1, 16);  ITER(2, 16);  ITER(3, 16);
    ITER(4, 16);  ITER(5, 16);  ITER(6, 16);  ITER(7, 16);
    ITER(8, 16);  ITER(9, 16);  ITER(10, 16); ITER(11, 16);
    ITER(12, 16); ITER(13, 16); ITER(14, 12); ITER(15, 0);

    #undef LOADA
    #undef LOADB
    #undef ITER

    // ---- epilogue: add beta, store fp32 (same pattern as round 2: clean)
    #pragma unroll
    for (int nf = 0; nf < 8; ++nf) {
        #pragma unroll
        for (int mf = 0; mf < 2; ++mf) {
            float* p = out + (size_t)(blk * 64 + wm * 32 + mf * 16 + fq * 4) * OUT_F
                           + wn * 128 + nf * 16 + fr;
            p[0 * OUT_F] = acc[mf][nf][0] + bv[nf];
            p[1 * OUT_F] = acc[mf][nf][1] + bv[nf];
            p[2 * OUT_F] = acc[mf][nf][2] + bv[nf];
            p[3 * OUT_F] = acc[mf][nf][3] + bv[nf];
        }
    }
}

extern "C" void kernel_launch(void* const* d_in, const int* in_sizes, int n_in,
                              void* d_out, int out_size, void* d_ws, size_t ws_size,
                              hipStream_t stream)
{
    const float* x       = (const float*)d_in[0];
    const float* z       = (const float*)d_in[1];
    const float* weight  = (const float*)d_in[2];
    const float* w_alpha = (const float*)d_in[3];
    const float* b_alpha = (const float*)d_in[4];
    const float* w_beta  = (const float*)d_in[5];
    const float* b_beta  = (const float*)d_in[6];
    float* out = (float*)d_out;

    unsigned short* wfragB = (unsigned short*)d_ws;          // 2 x 512 KiB
    float* alpha = (float*)((char*)d_ws + 1048576);          // 4 KiB
    float* beta  = alpha + 2 * IN_F;                         // 4 KiB

    prep1_kernel<<<8, 256, 0, stream>>>(z, w_alpha, b_alpha, w_beta, b_beta,
                                        alpha, beta);
    prep2_kernel<<<512, 256, 0, stream>>>(weight, alpha, wfragB);
    modlin_kernel<<<4096, 512, 0, stream>>>(x, wfragB, beta, out);
}

// Round 10
// 365.066 us; speedup vs baseline: 1.4842x; 1.4842x over previous
//
#include <hip/hip_runtime.h>

typedef __attribute__((ext_vector_type(4))) float f32x4;
typedef __attribute__((ext_vector_type(8))) short s16x8;

#define IN_F 512
#define OUT_F 512
#define STYLE_F 256

typedef __attribute__((address_space(1))) const void gvoid;
typedef __attribute__((address_space(3))) void svoid;

__device__ __forceinline__ unsigned short f2bf(float f) {
    unsigned int u = __builtin_bit_cast(unsigned int, f);
    u += 0x7FFFu + ((u >> 16) & 1u);   // round-to-nearest-even
    return (unsigned short)(u >> 16);
}

// pack 8 fp32 -> 8 bf16 (RNE) via v_cvt_pk_bf16_f32
__device__ __forceinline__ s16x8 cvt8(f32x4 a, f32x4 b) {
    union { unsigned int w[4]; s16x8 v; } u;
    asm("v_cvt_pk_bf16_f32 %0, %1, %2" : "=v"(u.w[0]) : "v"(a[0]), "v"(a[1]));
    asm("v_cvt_pk_bf16_f32 %0, %1, %2" : "=v"(u.w[1]) : "v"(a[2]), "v"(a[3]));
    asm("v_cvt_pk_bf16_f32 %0, %1, %2" : "=v"(u.w[2]) : "v"(b[0]), "v"(b[1]));
    asm("v_cvt_pk_bf16_f32 %0, %1, %2" : "=v"(u.w[3]) : "v"(b[2]), "v"(b[3]));
    return u.v;
}

// ---------------- prep1: alpha/beta GEMVs (2048 dots of length 256) --------
__global__ __launch_bounds__(256) void prep1_kernel(
    const float* __restrict__ z,
    const float* __restrict__ w_alpha,
    const float* __restrict__ b_alpha,
    const float* __restrict__ w_beta,
    const float* __restrict__ b_beta,
    float* __restrict__ alpha,
    float* __restrict__ beta)
{
    int gid = blockIdx.x * 256 + threadIdx.x;
    if (gid >= 2048) return;
    int t = gid & 1023;
    int b = t >> 9;
    int i = t & 511;
    const float* zr = z + b * STYLE_F;
    const float* wr = (gid < 1024 ? w_alpha : w_beta) + i * STYLE_F;
    float acc = 0.f;
    #pragma unroll 4
    for (int kk = 0; kk < STYLE_F; kk += 4) {
        float4 zv = *reinterpret_cast<const float4*>(zr + kk);
        float4 vv = *reinterpret_cast<const float4*>(wr + kk);
        acc += zv.x * vv.x + zv.y * vv.y + zv.z * vv.z + zv.w * vv.w;
    }
    if (gid < 1024) alpha[t] = acc + b_alpha[i];
    else            beta[t]  = acc + b_beta[i];
}

// ---------------- prep2: W * alpha_b -> bf16 fragment order, per batch -----
// wfragB[b] element index = (((ks*32 + nf)*64 + lane)*8 + e)
//   holds weight[n = nf*16 + (lane&15)][k = ks*32 + (lane>>4)*8 + e] * alpha[b][k]
__global__ __launch_bounds__(256) void prep2_kernel(
    const float* __restrict__ weight,
    const float* __restrict__ alpha,
    unsigned short* __restrict__ wfragB)
{
    int gid = blockIdx.x * 256 + threadIdx.x;   // 131072 threads total
    int b = gid >> 16;                          // 65536 threads per batch
    int f = (gid & 65535) << 2;
    int e0 = f & 7;                 // 0 or 4
    int l  = (f >> 3) & 63;
    int nf = (f >> 9) & 31;
    int ks = f >> 14;               // 0..15
    int n  = nf * 16 + (l & 15);
    int k  = ks * 32 + ((l >> 4) << 3) + e0;
    float4 wv = *reinterpret_cast<const float4*>(weight + n * IN_F + k);
    float4 av = *reinterpret_cast<const float4*>(alpha + b * IN_F + k);
    ushort4 o;
    o.x = f2bf(wv.x * av.x); o.y = f2bf(wv.y * av.y);
    o.z = f2bf(wv.z * av.z); o.w = f2bf(wv.w * av.w);
    *reinterpret_cast<ushort4*>(wfragB + b * 262144 + f) = o;
}

// ---------------- main GEMM: out = x_bf16 @ (W*alpha_b)^T + beta -----------
// MANY SMALL BLOCKS (m97-style TLP): 16384 blocks x 128 thr (2 waves),
// block tile 64 rows x 128 cols, BK=32, 16 K-steps. Wave tile 64x64,
// acc[4][4]=64 regs. ~6 blocks/CU resident -> independent barrier domains
// keep HBM busy while any one block drains at its __syncthreads().
// A: global_load_lds (4 instr/wave/step) into 2x8KB LDS bufs, pre-swizzled
//    source + XOR-swizzled ds_read (both-sides).
// B: L2-resident wfragB, plain dwordx4 loads.
__global__ __launch_bounds__(128, 3) void modlin_kernel(
    const float* __restrict__ x,
    const unsigned short* __restrict__ wfragB,
    const float* __restrict__ beta,
    float* __restrict__ out)
{
    // 2 bufs x (64 rows x 32 k fp32 = 8 KiB). Row = 128 B = 8 units of 16 B;
    // unit u of row r lives at slot u ^ (r & 7).
    __shared__ __align__(16) char lds[16384];

    const int tid = threadIdx.x;       // 0..127
    const int blk = blockIdx.x;        // 16384
    // XCD-bijective swizzle: each XCD sees one row-slab's 4 col-groups
    const int xcd  = blk & 7;
    const int tt   = blk >> 3;
    const int rowg = (tt >> 2) * 8 + xcd;   // 0..4095
    const int colg = tt & 3;                // 0..3
    const int b    = rowg >> 11;            // batch
    const size_t row0 = (size_t)rowg * 64;

    const int l  = tid & 63;
    const int w  = tid >> 6;           // wave 0..1 (col-half)
    const int fr = l & 15;
    const int fq = l >> 4;             // 0..3

    // ---- DMA source map: wave w, instr i, lane l ->
    //   row_local = w*32 + i*8 + (l>>3), slot = l&7, src unit = slot^(row&7)
    const int drl = l >> 3;
    const int su  = (l & 7) ^ (drl & 7);
    const float* xsrc = x + (row0 + (size_t)(w * 32 + drl)) * IN_F + su * 4;
    const int ldst = w * 4096;         // + i*1024 + buf*8192; HW adds lane*16

    // ---- ds_read byte addrs: frag mf, unit u in {2fq, 2fq+1}
    int va[8];
    #pragma unroll
    for (int mf = 0; mf < 4; ++mf) {
        int R = mf * 16 + fr;
        va[mf * 2 + 0] = R * 128 + ((((fq * 2) + 0) ^ (R & 7)) << 4);
        va[mf * 2 + 1] = R * 128 + ((((fq * 2) + 1) ^ (R & 7)) << 4);
    }

    // ---- B base: NF = colg*8 + w*4 + nf; byte = (ks*32+NF)*1024 + l*16
    const char* bbp = (const char*)wfragB + (size_t)b * 524288
                    + (size_t)(colg * 8 + w * 4) * 1024 + (size_t)l * 16;

    // ---- beta preload
    float bv[4];
    #pragma unroll
    for (int nf = 0; nf < 4; ++nf)
        bv[nf] = beta[b * OUT_F + colg * 128 + w * 64 + nf * 16 + fr];

    f32x4 acc[4][4];
    #pragma unroll
    for (int i = 0; i < 4; ++i)
        #pragma unroll
        for (int j = 0; j < 4; ++j)
            acc[i][j] = (f32x4){0.f, 0.f, 0.f, 0.f};

    // ---- prologue: DMA k-step 0 into buf 0
    #pragma unroll
    for (int i = 0; i < 4; ++i)
        __builtin_amdgcn_global_load_lds((gvoid*)(xsrc + i * 8 * IN_F),
            (svoid*)(lds + ldst + i * 1024), 16, 0, 0);

    // ---- 16 K-steps; __syncthreads() drains this step's DMA naturally
    for (int s = 0; s < 16; ++s) {
        __syncthreads();
        if (s < 15) {
            const float* xs = xsrc + (s + 1) * 32;
            char* ld = lds + (((s + 1) & 1) << 13) + ldst;
            #pragma unroll
            for (int i = 0; i < 4; ++i)
                __builtin_amdgcn_global_load_lds((gvoid*)(xs + i * 8 * IN_F),
                    (svoid*)(ld + i * 1024), 16, 0, 0);
        }

        const char* bp = bbp + (size_t)s * 32768;
        s16x8 bq[4];
        #pragma unroll
        for (int nf = 0; nf < 4; ++nf)
            bq[nf] = *reinterpret_cast<const s16x8*>(bp + nf * 1024);

        const char* ab = lds + ((s & 1) << 13);
        s16x8 a[4];
        #pragma unroll
        for (int mf = 0; mf < 4; ++mf) {
            f32x4 r0 = *reinterpret_cast<const f32x4*>(ab + va[mf * 2 + 0]);
            f32x4 r1 = *reinterpret_cast<const f32x4*>(ab + va[mf * 2 + 1]);
            a[mf] = cvt8(r0, r1);
        }

        #pragma unroll
        for (int nf = 0; nf < 4; ++nf)
            #pragma unroll
            for (int mf = 0; mf < 4; ++mf)
                acc[mf][nf] = __builtin_amdgcn_mfma_f32_16x16x32_bf16(
                    a[mf], bq[nf], acc[mf][nf], 0, 0, 0);
    }

    // ---- epilogue: add beta, store fp32
    float* ob = out + (row0 + fq * 4) * OUT_F + colg * 128 + w * 64 + fr;
    #pragma unroll
    for (int mf = 0; mf < 4; ++mf)
        #pragma unroll
        for (int nf = 0; nf < 4; ++nf) {
            float* p = ob + (size_t)(mf * 16) * OUT_F + nf * 16;
            p[0 * OUT_F] = acc[mf][nf][0] + bv[nf];
            p[1 * OUT_F] = acc[mf][nf][1] + bv[nf];
            p[2 * OUT_F] = acc[mf][nf][2] + bv[nf];
            p[3 * OUT_F] = acc[mf][nf][3] + bv[nf];
        }
}

extern "C" void kernel_launch(void* const* d_in, const int* in_sizes, int n_in,
                              void* d_out, int out_size, void* d_ws, size_t ws_size,
                              hipStream_t stream)
{
    const float* x       = (const float*)d_in[0];
    const float* z       = (const float*)d_in[1];
    const float* weight  = (const float*)d_in[2];
    const float* w_alpha = (const float*)d_in[3];
    const float* b_alpha = (const float*)d_in[4];
    const float* w_beta  = (const float*)d_in[5];
    const float* b_beta  = (const float*)d_in[6];
    float* out = (float*)d_out;

    unsigned short* wfragB = (unsigned short*)d_ws;          // 2 x 512 KiB
    float* alpha = (float*)((char*)d_ws + 1048576);          // 4 KiB
    float* beta  = alpha + 2 * IN_F;                         // 4 KiB

    prep1_kernel<<<8, 256, 0, stream>>>(z, w_alpha, b_alpha, w_beta, b_beta,
                                        alpha, beta);
    prep2_kernel<<<512, 256, 0, stream>>>(weight, alpha, wfragB);
    modlin_kernel<<<16384, 128, 0, stream>>>(x, wfragB, beta, out);
}